// Round 9
// baseline (683.001 us; speedup 1.0000x reference)
//
#include <hip/hip_runtime.h>
#include <hip/hip_cooperative_groups.h>
#include <hip/hip_bf16.h>
#include <type_traits>

static constexpr int T = 2048;
static constexpr int B = 4;
static constexpr int D = 1024;
static constexpr int E = 2 * D;     // 2048
static constexpr int M1 = T * B;    // 8192

typedef __attribute__((ext_vector_type(8))) short short8;   // 8 bf16 = 4 VGPRs (MFMA A/B frag)
typedef __attribute__((ext_vector_type(4))) float f32x4;    // MFMA C/D frag

__device__ inline ushort f2bf(float x) {
    __hip_bfloat16 h = __float2bfloat16(x);
    return __builtin_bit_cast(ushort, h);
}

__device__ inline void glds16(const void* g, void* l) {
    __builtin_amdgcn_global_load_lds(
        (const __attribute__((address_space(1))) void*)g,
        (__attribute__((address_space(3))) void*)l, 16, 0, 0);
}

// ===========================================================================
// 128x128-tile, BK=64, 4-wave 2-phase GEMM body (NT): proven structure.
//   C[m,n] = alpha * sum_k A[m,k]*Bt[n,k] + bias[n]
// smem arena: 32KB = As(16KB) + Bs(16KB). XOR chunk swizzle as before.
// NOTE: callers must NOT constrain occupancy via __launch_bounds__ min-waves:
// R8 showed (256,4) caps unified VGPR at 128 -> inner-loop spills -> 2.5x slow.
// ===========================================================================
template <typename OT>
__device__ __forceinline__ void gemm_body(char* __restrict__ smem,
    const ushort* __restrict__ A, const ushort* __restrict__ Bt,
    OT* __restrict__ C, const float* __restrict__ bias,
    int K, int lda, int ldb, int ldc, float alpha, int bm, int bn)
{
    ushort* As = (ushort*)smem;            // 16KB
    ushort* Bs = (ushort*)(smem + 16384);  // 16KB

    const int tid  = threadIdx.x;
    const int lane = tid & 63;
    const int wave = tid >> 6;        // 0..3
    const int wm = (wave & 1) * 64;
    const int wn = (wave >> 1) * 64;

    f32x4 acc[4][4] = {};

    const int srow  = lane >> 3;                         // 0..7 within 8-row gang
    const int sElem = (((lane & 7) ^ (lane >> 3))) * 8;  // swizzled global elem offset
    const int rbase = ((lane >> 4) ^ (lane & 7)) * 8;    // kb=0 read chunk
    const int rxor4 = 4 * 8;                             // kb=1 flips bit2 of chunk

    for (int k0 = 0; k0 < K; k0 += 64) {
        __syncthreads();
#pragma unroll
        for (int j = 0; j < 4; ++j) {
            const int r = wave * 32 + j * 8;             // gang base row
            glds16(Bt + (long long)(bn + r + srow) * ldb + (k0 + sElem),
                   (void*)&Bs[r * 64]);
            glds16(A + (long long)(bm + r + srow) * lda + (k0 + sElem),
                   (void*)&As[r * 64]);
        }
        __syncthreads();

#pragma unroll
        for (int kb = 0; kb < 2; ++kb) {
            const int rElem = rbase ^ (kb ? rxor4 : 0);
            short8 af[4], bf[4];
#pragma unroll
            for (int i = 0; i < 4; ++i) {
                const int m = wm + i * 16 + (lane & 15);
                af[i] = *(const short8*)&As[m * 64 + rElem];
            }
#pragma unroll
            for (int j = 0; j < 4; ++j) {
                const int n = wn + j * 16 + (lane & 15);
                bf[j] = *(const short8*)&Bs[n * 64 + rElem];
            }
#pragma unroll
            for (int i = 0; i < 4; ++i)
#pragma unroll
                for (int j = 0; j < 4; ++j)
                    acc[i][j] = __builtin_amdgcn_mfma_f32_16x16x32_bf16(af[i], bf[j], acc[i][j], 0, 0, 0);
        }
    }
    __syncthreads();   // protect smem before caller reuses it

    // epilogue: C/D layout col=lane&15, row=(lane>>4)*4+r  [verified m89]
#pragma unroll
    for (int j = 0; j < 4; ++j) {
        const int col = bn + wn + j * 16 + (lane & 15);
        const float bv = bias ? bias[col] : 0.0f;
#pragma unroll
        for (int i = 0; i < 4; ++i) {
            const int row0 = bm + wm + i * 16 + ((lane >> 4) << 2);
#pragma unroll
            for (int r = 0; r < 4; ++r) {
                const float v = acc[i][j][r] * alpha + bv;
                if constexpr (std::is_same<OT, float>::value)
                    C[(long long)(row0 + r) * ldc + col] = v;
                else
                    C[(long long)(row0 + r) * ldc + col] = f2bf(v);
            }
        }
    }
}

// fp32 -> bf16 cast of one 1024-float block
__device__ __forceinline__ void cast_blk(const float* __restrict__ s,
                                         ushort* __restrict__ d, int blk) {
    const int i = blk * 256 + threadIdx.x;
    const float4 v = ((const float4*)s)[i];
    ushort4 o;
    o.x = f2bf(v.x); o.y = f2bf(v.y); o.z = f2bf(v.z); o.w = f2bf(v.w);
    ((ushort4*)d)[i] = o;
}

// vt[b][d][s] = kv[(s*B+b)*E + D + d]   (64x64 LDS tile transpose)
__device__ __forceinline__ void transpose_body(char* __restrict__ smem,
                                               const ushort* __restrict__ kv,
                                               ushort* __restrict__ vt,
                                               int s0, int d0, int b) {
    typedef ushort row65[65];
    row65* tile = (row65*)smem;               // 64x65 ushorts = 8.3KB
    const int t = threadIdx.x;
    __syncthreads();                          // smem handoff from previous use
    const int dl = (t & 15) * 4, sl = t >> 4;
#pragma unroll
    for (int p = 0; p < 4; ++p) {
        const int s = sl + p * 16;
        const ushort4 v = *(const ushort4*)&kv[((long long)(s0 + s) * B + b) * E + D + d0 + dl];
        tile[s][dl + 0] = v.x; tile[s][dl + 1] = v.y;
        tile[s][dl + 2] = v.z; tile[s][dl + 3] = v.w;
    }
    __syncthreads();
    const int dl2 = t >> 4, sl2 = (t & 15) * 4;
#pragma unroll
    for (int p = 0; p < 4; ++p) {
        const int d = dl2 + p * 16;
        ushort4 o;
        o.x = tile[sl2 + 0][d]; o.y = tile[sl2 + 1][d];
        o.z = tile[sl2 + 2][d]; o.w = tile[sl2 + 3][d];
        *(ushort4*)&vt[(long long)b * D * T + (long long)(d0 + d) * T + s0 + sl2] = o;
    }
}

// fp32 softmax over one row of length T=2048 (256 threads), in-place + bf16 copy
__device__ __forceinline__ void softmax_body(char* __restrict__ smem,
                                             float* __restrict__ W,
                                             ushort* __restrict__ Pbf,
                                             long long row) {
    float* red = (float*)smem;   // 4 floats
    float* p  = W + row * (long long)T;
    ushort* pb = Pbf + row * (long long)T;
    const int tid = threadIdx.x;
    __syncthreads();             // smem handoff (prev iteration / stage)

    float4 v0 = ((const float4*)p)[tid];
    float4 v1 = ((const float4*)p)[tid + 256];

    float m = fmaxf(fmaxf(fmaxf(v0.x, v0.y), fmaxf(v0.z, v0.w)),
                    fmaxf(fmaxf(v1.x, v1.y), fmaxf(v1.z, v1.w)));
#pragma unroll
    for (int off = 1; off < 64; off <<= 1) m = fmaxf(m, __shfl_xor(m, off));

    const int wid = tid >> 6, lane = tid & 63;
    if (lane == 0) red[wid] = m;
    __syncthreads();
    m = fmaxf(fmaxf(red[0], red[1]), fmaxf(red[2], red[3]));
    __syncthreads();

    v0.x = expf(v0.x - m); v0.y = expf(v0.y - m);
    v0.z = expf(v0.z - m); v0.w = expf(v0.w - m);
    v1.x = expf(v1.x - m); v1.y = expf(v1.y - m);
    v1.z = expf(v1.z - m); v1.w = expf(v1.w - m);

    float s = v0.x + v0.y + v0.z + v0.w + v1.x + v1.y + v1.z + v1.w;
#pragma unroll
    for (int off = 1; off < 64; off <<= 1) s += __shfl_xor(s, off);
    if (lane == 0) red[wid] = s;
    __syncthreads();
    s = red[0] + red[1] + red[2] + red[3];

    const float inv = 1.0f / s;
    v0.x *= inv; v0.y *= inv; v0.z *= inv; v0.w *= inv;
    v1.x *= inv; v1.y *= inv; v1.z *= inv; v1.w *= inv;

    ((float4*)p)[tid] = v0;
    ((float4*)p)[tid + 256] = v1;

    ushort4 o0, o1;
    o0.x = f2bf(v0.x); o0.y = f2bf(v0.y); o0.z = f2bf(v0.z); o0.w = f2bf(v0.w);
    o1.x = f2bf(v1.x); o1.y = f2bf(v1.y); o1.z = f2bf(v1.z); o1.w = f2bf(v1.w);
    ((ushort4*)pb)[tid] = o0;
    ((ushort4*)pb)[tid + 256] = o1;
}

// ===========================================================================
// Cooperative persistent mega-kernel: all 6 stages, grid.sync() between.
// Stages are PURE (no cross-stage co-scheduling — R7 L2-pollution lesson).
// PLAIN __launch_bounds__(256): R8's (256,4) forced a 128-VGPR unified cap
// (acc alone = 64) -> inner-loop spills -> 2.5x regression. Grid size is
// taken from the occupancy API so coop co-residency holds at natural regs.
// ===========================================================================
__global__ __launch_bounds__(256) void mega(
    const float* __restrict__ query, const float* __restrict__ x,
    const float* __restrict__ w_in, const float* __restrict__ b_in,
    const float* __restrict__ w_out, const float* __restrict__ b_out,
    float* __restrict__ out_attn, float* __restrict__ out_w,
    ushort* xbf, ushort* qbf, ushort* wibf, ushort* wobf,
    ushort* kv, ushort* Pbf, ushort* vt, ushort* amid)
{
    __shared__ __align__(16) char smem[32768];
    cooperative_groups::grid_group grid = cooperative_groups::this_grid();
    const int bid = blockIdx.x, gsz = gridDim.x;

    // stage 0: casts (x, w_in, q, w_out)
    for (int i = bid; i < 8192; i += gsz) cast_blk(x, xbf, i);
    for (int i = bid; i < 2048; i += gsz) cast_blk(w_in, wibf, i);
    for (int i = bid; i < 8192; i += gsz) cast_blk(query, qbf, i);
    for (int i = bid; i < 1024; i += gsz) cast_blk(w_out, wobf, i);
    grid.sync();

    // stage 1: G1  kv = X.Win^T + b_in   (1024 tiles: 64 bm x 16 bn)
    for (int t0 = bid; t0 < 1024; t0 += gsz) {
        const int tt = (t0 & 7) * 128 + (t0 >> 3);      // XCD-contiguous stripes
        gemm_body<ushort>(smem, xbf, wibf, kv, b_in, D, D, D, E, 1.0f,
                          (tt >> 4) * 128, (tt & 15) * 128);
    }
    grid.sync();

    // stage 2: QK logits (1024 tiles: 4b x 16bm x 16bn) then V-transpose
    for (int t0 = bid; t0 < 1024; t0 += gsz) {
        const int tt = (t0 & 7) * 128 + (t0 >> 3);
        const int b = tt >> 8, t = tt & 255;
        gemm_body<float>(smem, qbf + (long long)b * D, kv + (long long)b * E,
                         out_w + (long long)b * T * T, nullptr,
                         D, B * D, B * E, T, 0.03125f,
                         (t >> 4) * 128, (t & 15) * 128);
    }
    for (int s = bid; s < 2048; s += gsz) {
        const int b = s >> 9, idx = s & 511;
        transpose_body(smem, kv, vt, (idx & 31) * 64, (idx >> 5) * 64, b);
    }
    grid.sync();

    // stage 3: softmax (8192 rows) in-place + bf16 Pbf (overwrites kv: dead)
    for (int r = bid; r < 8192; r += gsz)
        softmax_body(smem, out_w, Pbf, r);
    grid.sync();

    // stage 4: PV  amid = P.vt^T  (512 tiles: 4b x 16bm x 8bn)
    for (int t0 = bid; t0 < 512; t0 += gsz) {
        const int tt = (t0 & 7) * 64 + (t0 >> 3);
        const int b = tt >> 7, rem = tt & 127;
        gemm_body<ushort>(smem, Pbf + (long long)b * T * T,
                          vt + (long long)b * D * T,
                          amid + (long long)b * D, nullptr,
                          T, T, T, B * D, 1.0f,
                          (rem >> 3) * 128, (rem & 7) * 128);
    }
    grid.sync();

    // stage 5: OP  out = amid.Wout^T + b_out  (512 tiles: 64 bm x 8 bn)
    for (int t0 = bid; t0 < 512; t0 += gsz) {
        const int tt = (t0 & 7) * 64 + (t0 >> 3);
        gemm_body<float>(smem, amid, wobf, out_attn, b_out,
                         D, D, D, D, 1.0f, (tt >> 3) * 128, (tt & 7) * 128);
    }
}

// ======================= fallback multi-launch path ========================
__global__ __launch_bounds__(256) void cast_all(
    const float* __restrict__ s0, ushort* __restrict__ d0, int n0,
    const float* __restrict__ s1, ushort* __restrict__ d1, int n1,
    const float* __restrict__ s2, ushort* __restrict__ d2, int n2,
    const float* __restrict__ s3, ushort* __restrict__ d3, int n3)
{
    int blk = blockIdx.x;
    const float* s; ushort* d;
    if (blk < n0) { s = s0; d = d0; }
    else if ((blk -= n0) < n1) { s = s1; d = d1; }
    else if ((blk -= n1) < n2) { s = s2; d = d2; }
    else { blk -= n2; s = s3; d = d3; }
    cast_blk(s, d, blk);
}

template <typename OT>
__global__ __launch_bounds__(256) void mfma_gemm_nt(
    const ushort* __restrict__ A, const ushort* __restrict__ Bt,
    OT* __restrict__ C, const float* __restrict__ bias,
    int K, int lda, int ldb, int ldc,
    long long aBatch, long long bBatch, long long cBatch, float alpha)
{
    __shared__ __align__(16) char smem[32768];
    int id = blockIdx.y * gridDim.x + blockIdx.x;
    const int q = (gridDim.x * gridDim.y) >> 3;
    id = (id & 7) * q + (id >> 3);
    const int bm_i = id / gridDim.x;
    const int bn_i = id - bm_i * gridDim.x;
    gemm_body<OT>(smem, A + blockIdx.z * aBatch, Bt + blockIdx.z * bBatch,
                  C + blockIdx.z * cBatch, bias,
                  K, lda, ldb, ldc, alpha, bm_i * 128, bn_i * 128);
}

__global__ __launch_bounds__(256) void transpose_v(const ushort* __restrict__ kv,
                                                   ushort* __restrict__ vt)
{
    __shared__ __align__(16) char smem[8320];
    transpose_body(smem, kv, vt, blockIdx.x * 64, blockIdx.y * 64, blockIdx.z);
}

__global__ __launch_bounds__(256) void softmax_kernel(float* __restrict__ W,
                                                      ushort* __restrict__ Pbf)
{
    __shared__ __align__(16) char smem[16];
    softmax_body(smem, W, Pbf, blockIdx.x);
}

extern "C" void kernel_launch(void* const* d_in, const int* in_sizes, int n_in,
                              void* d_out, int out_size, void* d_ws, size_t ws_size,
                              hipStream_t stream)
{
    const float* query = (const float*)d_in[0];   // (T,B,D)
    const float* x     = (const float*)d_in[1];   // (T,B,D)
    const float* w_in  = (const float*)d_in[2];   // (2D,D)
    const float* b_in  = (const float*)d_in[3];   // (2D,)
    const float* w_out = (const float*)d_in[4];   // (D,D)
    const float* b_out = (const float*)d_in[5];   // (D,)

    float* out_attn = (float*)d_out;                      // (T,B,D) fp32
    float* out_w    = out_attn + (long long)T * B * D;    // (B,T,T) fp32

    // workspace layout (unchanged):
    //  [0,16)   xbf (cast->G1)            then amid (PV->OP)
    //  [16,32)  qbf  [32,36) wibf  [36,38) wobf
    //  [38,70)  kv (G1->QK/transpose)     then Pbf (softmax->PV)
    //  [70,86)  vt (transpose->PV)
    char* ws = (char*)d_ws;
    ushort* xbf  = (ushort*)(ws);
    ushort* amid = (ushort*)(ws);
    ushort* qbf  = (ushort*)(ws + (16ll << 20));
    ushort* wibf = (ushort*)(ws + (32ll << 20));
    ushort* wobf = (ushort*)(ws + (36ll << 20));
    ushort* kv   = (ushort*)(ws + (38ll << 20));
    ushort* Pbf  = (ushort*)(ws + (38ll << 20));
    ushort* vt   = (ushort*)(ws + (70ll << 20));

    // one-time: co-resident grid size for the cooperative launch
    static int gridsz = 0;
    if (gridsz == 0) {
        int nb = 0;
        if (hipOccupancyMaxActiveBlocksPerMultiprocessor(&nb, mega, 256, 0) != hipSuccess || nb <= 0)
            nb = 2;                                   // conservative
        hipDeviceProp_t prop;
        int cus = 256;
        if (hipGetDeviceProperties(&prop, 0) == hipSuccess) cus = prop.multiProcessorCount;
        gridsz = nb * cus;
        if (gridsz > 1024) gridsz = 1024;
        if (gridsz < 64)   gridsz = 64;
    }

    const float *a0 = query, *a1 = x, *a2 = w_in, *a3 = b_in, *a4 = w_out, *a5 = b_out;
    float *a6 = out_attn, *a7 = out_w;
    ushort *a8 = xbf, *a9 = qbf, *a10 = wibf, *a11 = wobf,
           *a12 = kv, *a13 = Pbf, *a14 = vt, *a15 = amid;
    void* args[] = {&a0,&a1,&a2,&a3,&a4,&a5,&a6,&a7,
                    &a8,&a9,&a10,&a11,&a12,&a13,&a14,&a15};

    hipError_t err = hipLaunchCooperativeKernel(
        mega, dim3(gridsz), dim3(256), args, 0, stream);

    if (err != hipSuccess) {
        // fallback: proven 7-launch path (R4-equivalent, ~354us)
        cast_all<<<dim3(8192 + 2048 + 8192 + 1024), 256, 0, stream>>>(
            x, xbf, 8192, w_in, wibf, 2048, query, qbf, 8192, w_out, wobf, 1024);
        mfma_gemm_nt<ushort><<<dim3(E / 128, M1 / 128, 1), 256, 0, stream>>>(
            xbf, wibf, kv, b_in, D, D, D, E, 0, 0, 0, 1.0f);
        transpose_v<<<dim3(T / 64, D / 64, B), 256, 0, stream>>>(kv, vt);
        mfma_gemm_nt<float><<<dim3(T / 128, T / 128, B), 256, 0, stream>>>(
            qbf, kv, out_w, nullptr, D, B * D, B * E, T,
            (long long)D, (long long)E, (long long)T * T, 0.03125f);
        softmax_kernel<<<dim3(B * T), 256, 0, stream>>>(out_w, Pbf);
        mfma_gemm_nt<ushort><<<dim3(D / 128, T / 128, B), 256, 0, stream>>>(
            Pbf, vt, amid, nullptr, T, T, T, B * D,
            (long long)T * T, (long long)D * T, (long long)D, 1.0f);
        mfma_gemm_nt<float><<<dim3(D / 128, M1 / 128, 1), 256, 0, stream>>>(
            amid, wobf, out_attn, b_out, D, D, D, D, 0, 0, 0, 1.0f);
    }
}

// Round 10
// 352.023 us; speedup vs baseline: 1.9402x; 1.9402x over previous
//
#include <hip/hip_runtime.h>
#include <hip/hip_bf16.h>
#include <type_traits>

static constexpr int T = 2048;
static constexpr int B = 4;
static constexpr int D = 1024;
static constexpr int E = 2 * D;     // 2048
static constexpr int M1 = T * B;    // 8192

typedef __attribute__((ext_vector_type(8))) short short8;   // 8 bf16 = 4 VGPRs (MFMA A/B frag)
typedef __attribute__((ext_vector_type(4))) float f32x4;    // MFMA C/D frag

__device__ inline ushort f2bf(float x) {
    __hip_bfloat16 h = __float2bfloat16(x);
    return __builtin_bit_cast(ushort, h);
}

__device__ inline void glds16(const void* g, void* l) {
    __builtin_amdgcn_global_load_lds(
        (const __attribute__((address_space(1))) void*)g,
        (__attribute__((address_space(3))) void*)l, 16, 0, 0);
}

// XCD-aware bijective block swizzle (T1). ALL grids below have
// gridDim.x == 8 and per-z-slice block count divisible by 8, so XCD x
// (which receives original ids ≡ x mod 8) gets a contiguous bm-stripe:
// A-panels are fetched by exactly one XCD instead of all 8.
__device__ inline void xcd_swizzle(int& bn_i, int& bm_i) {
    int id = blockIdx.y * 8 + blockIdx.x;
    id = (id & 7) * gridDim.y + (id >> 3);   // bijective: nwg % 8 == 0
    bn_i = id & 7;
    bm_i = id >> 3;
}

// ===========================================================================
// 128x128-tile, BK=64, 4-wave 2-phase GEMM (NT): proven baseline structure.
//   C[m,n] = alpha * sum_k A[m,k]*Bt[n,k] + bias[n]
// LDS rows are 64 bf16 = 128B. XOR chunk swizzle: global 16B-chunk c of
// tile-row m lives at LDS chunk c ^ (m&7)  -> 2-way bank aliasing = free.
// ===========================================================================
template <typename OT>
__global__ __launch_bounds__(256) void mfma_gemm_nt(
    const ushort* __restrict__ A, const ushort* __restrict__ Bt,
    OT* __restrict__ C, const float* __restrict__ bias,
    int K, int lda, int ldb, int ldc,
    long long aBatch, long long bBatch, long long cBatch, float alpha)
{
    __shared__ ushort As[128 * 64];   // 16KB
    __shared__ ushort Bs[128 * 64];   // 16KB

    const int tid  = threadIdx.x;
    const int lane = tid & 63;
    const int wave = tid >> 6;        // 0..3
    const int wm = (wave & 1) * 64;
    const int wn = (wave >> 1) * 64;

    int bn_i, bm_i;
    xcd_swizzle(bn_i, bm_i);
    const int bm = bm_i * 128;
    const int bn = bn_i * 128;
    A  += blockIdx.z * aBatch;
    Bt += blockIdx.z * bBatch;
    C  += blockIdx.z * cBatch;

    f32x4 acc[4][4] = {};

    const int srow  = lane >> 3;                         // 0..7 within 8-row gang
    const int sElem = (((lane & 7) ^ (lane >> 3))) * 8;  // swizzled global elem offset
    const int rbase = ((lane >> 4) ^ (lane & 7)) * 8;    // kb=0 read chunk
    const int rxor4 = 4 * 8;                             // kb=1 flips bit2 of chunk

    for (int k0 = 0; k0 < K; k0 += 64) {
        __syncthreads();
#pragma unroll
        for (int j = 0; j < 4; ++j) {
            const int r = wave * 32 + j * 8;             // gang base row
            glds16(Bt + (long long)(bn + r + srow) * ldb + (k0 + sElem),
                   (void*)&Bs[r * 64]);
            glds16(A + (long long)(bm + r + srow) * lda + (k0 + sElem),
                   (void*)&As[r * 64]);
        }
        __syncthreads();

#pragma unroll
        for (int kb = 0; kb < 2; ++kb) {
            const int rElem = rbase ^ (kb ? rxor4 : 0);
            short8 af[4], bf[4];
#pragma unroll
            for (int i = 0; i < 4; ++i) {
                const int m = wm + i * 16 + (lane & 15);
                af[i] = *(const short8*)&As[m * 64 + rElem];
            }
#pragma unroll
            for (int j = 0; j < 4; ++j) {
                const int n = wn + j * 16 + (lane & 15);
                bf[j] = *(const short8*)&Bs[n * 64 + rElem];
            }
#pragma unroll
            for (int i = 0; i < 4; ++i)
#pragma unroll
                for (int j = 0; j < 4; ++j)
                    acc[i][j] = __builtin_amdgcn_mfma_f32_16x16x32_bf16(af[i], bf[j], acc[i][j], 0, 0, 0);
        }
    }

    // epilogue: C/D layout col=lane&15, row=(lane>>4)*4+r  [verified m89]
#pragma unroll
    for (int j = 0; j < 4; ++j) {
        const int col = bn + wn + j * 16 + (lane & 15);
        const float bv = bias ? bias[col] : 0.0f;
#pragma unroll
        for (int i = 0; i < 4; ++i) {
            const int row0 = bm + wm + i * 16 + ((lane >> 4) << 2);
#pragma unroll
            for (int r = 0; r < 4; ++r) {
                const float v = acc[i][j][r] * alpha + bv;
                if constexpr (std::is_same<OT, float>::value)
                    C[(long long)(row0 + r) * ldc + col] = v;
                else
                    C[(long long)(row0 + r) * ldc + col] = f2bf(v);
            }
        }
    }
}

// ===========================================================================
// 256x256-tile, BK=64, 8-wave (2M x 4N), 8-phase counted-vmcnt GEMM (NT).
// Schedule per K-tile t (parity P=t&1), 4 phases x 2 barriers; B-halves of
// t+1 staged in ph1/ph2 (opposite parity, always safe); A-halves of t+2
// staged in ph4 (same parity; safe: all A-reads of tile t completed by ph3's
// dep-wait + trailing barrier). vmcnt(4) once per tile (never 0 mid-loop).
// ===========================================================================

#define STAGE_A(p_, half_, t_) do {                                           \
    const int k0_ = (t_) << 6;                                                \
    _Pragma("unroll")                                                         \
    for (int i_ = 0; i_ < 2; ++i_) {                                          \
        const int r_ = (half_) * 128 + i_ * 64 + wave * 8;                    \
        glds16(A + ((bm + r_ + srow) * lda + k0_ + sElem),                    \
               (void*)&As[(p_) * 16384 + r_ * 64]);                           \
    } } while (0)

#define STAGE_B(p_, half_, t_) do {                                           \
    const int k0_ = (t_) << 6;                                                \
    _Pragma("unroll")                                                         \
    for (int i_ = 0; i_ < 2; ++i_) {                                          \
        const int r_ = (half_) * 128 + i_ * 64 + wave * 8;                    \
        glds16(Bt + ((bn + r_ + srow) * ldb + k0_ + sElem),                   \
               (void*)&Bs[(p_) * 16384 + r_ * 64]);                           \
    } } while (0)

#define READ_A(MOFF)                                                          \
    _Pragma("unroll") for (int i = 0; i < 4; ++i) {                           \
        const int m_ = wm + (MOFF) + i * 16 + l15;                            \
        af_[i][0] = *(const short8*)&as_[m_ * 64 + rbase];                    \
        af_[i][1] = *(const short8*)&as_[m_ * 64 + (rbase ^ 32)];             \
    }

#define READ_B(JOFF)                                                          \
    _Pragma("unroll") for (int j = 0; j < 2; ++j) {                           \
        const int n_ = wn + ((JOFF) + j) * 16 + l15;                          \
        bf_[(JOFF) + j][0] = *(const short8*)&bs_[n_ * 64 + rbase];           \
        bf_[(JOFF) + j][1] = *(const short8*)&bs_[n_ * 64 + (rbase ^ 32)];    \
    }

#define MFMA_QUAD(IOFF, JOFF)                                                 \
    _Pragma("unroll") for (int i = 0; i < 4; ++i)                             \
    _Pragma("unroll") for (int j = 0; j < 2; ++j)                             \
    _Pragma("unroll") for (int kb = 0; kb < 2; ++kb)                          \
        acc[(IOFF) + i][(JOFF) + j] = __builtin_amdgcn_mfma_f32_16x16x32_bf16(\
            af_[i][kb], bf_[(JOFF) + j][kb], acc[(IOFF) + i][(JOFF) + j], 0, 0, 0)

#define TILE(P_, TT_) {                                                       \
    const ushort* as_ = As + (P_) * 16384;                                    \
    const ushort* bs_ = Bs + (P_) * 16384;                                    \
    short8 af_[4][2], bf_[4][2];                                              \
    /* phase 1 */                                                             \
    READ_A(0)                                                                 \
    READ_B(0)                                                                 \
    if ((TT_) + 1 < NT) { STAGE_B((P_) ^ 1, 0, (TT_) + 1); }                  \
    __builtin_amdgcn_s_barrier();                                             \
    __builtin_amdgcn_s_setprio(1);                                            \
    MFMA_QUAD(0, 0);                                                          \
    __builtin_amdgcn_s_setprio(0);                                            \
    __builtin_amdgcn_s_barrier();                                             \
    /* phase 2 */                                                             \
    READ_B(2)                                                                 \
    if ((TT_) + 1 < NT) { STAGE_B((P_) ^ 1, 1, (TT_) + 1); }                  \
    __builtin_amdgcn_s_barrier();                                             \
    __builtin_amdgcn_s_setprio(1);                                            \
    MFMA_QUAD(0, 2);                                                          \
    __builtin_amdgcn_s_setprio(0);                                            \
    __builtin_amdgcn_s_barrier();                                             \
    /* phase 3 */                                                             \
    READ_A(64)                                                                \
    __builtin_amdgcn_s_barrier();                                             \
    __builtin_amdgcn_s_setprio(1);                                            \
    MFMA_QUAD(4, 0);                                                          \
    __builtin_amdgcn_s_setprio(0);                                            \
    __builtin_amdgcn_s_barrier();                                             \
    /* phase 4 */                                                             \
    if ((TT_) + 2 < NT) { STAGE_A((P_), 0, (TT_) + 2); STAGE_A((P_), 1, (TT_) + 2); } \
    __builtin_amdgcn_s_barrier();                                             \
    __builtin_amdgcn_s_setprio(1);                                            \
    MFMA_QUAD(4, 2);                                                          \
    __builtin_amdgcn_s_setprio(0);                                            \
    if ((TT_) + 2 < NT)      { asm volatile("s_waitcnt vmcnt(4)" ::: "memory"); } \
    else if ((TT_) + 1 < NT) { asm volatile("s_waitcnt vmcnt(0)" ::: "memory"); } \
    __builtin_amdgcn_s_barrier();                                             \
}

template <typename OT>
__global__ __launch_bounds__(512, 2) void gemm256(
    const ushort* __restrict__ A, const ushort* __restrict__ Bt,
    OT* __restrict__ C, const float* __restrict__ bias,
    int K, int lda, int ldb, int ldc,
    long long aBatch, long long bBatch, long long cBatch, float alpha)
{
    extern __shared__ ushort lds[];
    ushort* As = lds;                 // [2][256*64]
    ushort* Bs = lds + 2 * 16384;     // [2][256*64]

    const int tid  = threadIdx.x;
    const int lane = tid & 63;
    const int wave = tid >> 6;            // 0..7
    const int wm = (wave >> 2) * 128;     // 0 / 128
    const int wn = (wave & 3) * 64;       // 0 / 64 / 128 / 192
    const int l15 = lane & 15;

    int bn_i, bm_i;
    xcd_swizzle(bn_i, bm_i);
    const int bm = bm_i * 256;
    const int bn = bn_i * 256;
    A  += blockIdx.z * aBatch;
    Bt += blockIdx.z * bBatch;
    C  += blockIdx.z * cBatch;

    f32x4 acc[8][4] = {};

    const int srow  = lane >> 3;                         // row within 8-row gang
    const int sElem = ((lane & 7) ^ (lane >> 3)) * 8;    // swizzled global elem offset
    const int rbase = ((lane >> 4) ^ (lane & 7)) * 8;    // kb=0 read chunk (elems)

    const int NT = K >> 6;

    // prologue: tile0 fully + tile1's A halves in flight
    STAGE_A(0, 0, 0); STAGE_A(0, 1, 0);
    STAGE_B(0, 0, 0); STAGE_B(0, 1, 0);
    if (NT > 1) {
        STAGE_A(1, 0, 1); STAGE_A(1, 1, 1);
        asm volatile("s_waitcnt vmcnt(4)" ::: "memory");
    } else {
        asm volatile("s_waitcnt vmcnt(0)" ::: "memory");
    }
    __builtin_amdgcn_s_barrier();

    for (int t = 0; t < NT; t += 2) {   // NT even (K=1024/2048)
        TILE(0, t)
        TILE(1, t + 1)
    }

    // epilogue: C/D layout col=lane&15, row=(lane>>4)*4+r  [verified m89]
#pragma unroll
    for (int j = 0; j < 4; ++j) {
        const int col = bn + wn + j * 16 + l15;
        const float bv = bias ? bias[col] : 0.0f;
#pragma unroll
        for (int i = 0; i < 8; ++i) {
            const int row0 = bm + wm + i * 16 + ((lane >> 4) << 2);
#pragma unroll
            for (int r = 0; r < 4; ++r) {
                const float v = acc[i][j][r] * alpha + bv;
                if constexpr (std::is_same<OT, float>::value)
                    C[(long long)(row0 + r) * ldc + col] = v;
                else
                    C[(long long)(row0 + r) * ldc + col] = f2bf(v);
            }
        }
    }
}

#undef TILE
#undef MFMA_QUAD
#undef READ_A
#undef READ_B
#undef STAGE_A
#undef STAGE_B

// all four fp32->bf16 casts in one launch (region select by block index)
__global__ __launch_bounds__(256) void cast_all(
    const float* __restrict__ s0, ushort* __restrict__ d0, int n0,
    const float* __restrict__ s1, ushort* __restrict__ d1, int n1,
    const float* __restrict__ s2, ushort* __restrict__ d2, int n2,
    const float* __restrict__ s3, ushort* __restrict__ d3, int n3)
{
    int blk = blockIdx.x;
    const float* s; ushort* d;
    if (blk < n0) { s = s0; d = d0; }
    else if ((blk -= n0) < n1) { s = s1; d = d1; }
    else if ((blk -= n1) < n2) { s = s2; d = d2; }
    else { blk -= n2; s = s3; d = d3; }
    const int i = blk * 256 + threadIdx.x;
    const float4 v = ((const float4*)s)[i];
    ushort4 o;
    o.x = f2bf(v.x); o.y = f2bf(v.y); o.z = f2bf(v.z); o.w = f2bf(v.w);
    ((ushort4*)d)[i] = o;
}

// vt[b][d][s] = kv[(s*B+b)*E + D + d]   (64x64 LDS tile transpose per block)
__global__ __launch_bounds__(256) void transpose_v(const ushort* __restrict__ kv,
                                                   ushort* __restrict__ vt)
{
    __shared__ ushort tile[64][65];
    const int s0 = blockIdx.x * 64, d0 = blockIdx.y * 64, b = blockIdx.z;
    const int t = threadIdx.x;
    const int dl = (t & 15) * 4, sl = t >> 4;
#pragma unroll
    for (int p = 0; p < 4; ++p) {
        const int s = sl + p * 16;
        const ushort4 v = *(const ushort4*)&kv[((long long)(s0 + s) * B + b) * E + D + d0 + dl];
        tile[s][dl + 0] = v.x; tile[s][dl + 1] = v.y;
        tile[s][dl + 2] = v.z; tile[s][dl + 3] = v.w;
    }
    __syncthreads();
    const int dl2 = t >> 4, sl2 = (t & 15) * 4;
#pragma unroll
    for (int p = 0; p < 4; ++p) {
        const int d = dl2 + p * 16;
        ushort4 o;
        o.x = tile[sl2 + 0][d]; o.y = tile[sl2 + 1][d];
        o.z = tile[sl2 + 2][d]; o.w = tile[sl2 + 3][d];
        *(ushort4*)&vt[(long long)b * D * T + (long long)(d0 + d) * T + s0 + sl2] = o;
    }
}

// in-place fp32 softmax over rows of length T=2048, one 256-thr block per row.
// Also emits a bf16 copy of the row into Pbf for the PV GEMM.
__global__ __launch_bounds__(256) void softmax_kernel(float* __restrict__ W,
                                                      ushort* __restrict__ Pbf)
{
    const long long row = blockIdx.x;
    float* p = W + row * (long long)T;
    ushort* pb = Pbf + row * (long long)T;
    const int tid = threadIdx.x;

    float4 v0 = ((const float4*)p)[tid];
    float4 v1 = ((const float4*)p)[tid + 256];

    float m = fmaxf(fmaxf(fmaxf(v0.x, v0.y), fmaxf(v0.z, v0.w)),
                    fmaxf(fmaxf(v1.x, v1.y), fmaxf(v1.z, v1.w)));
#pragma unroll
    for (int off = 1; off < 64; off <<= 1) m = fmaxf(m, __shfl_xor(m, off));

    __shared__ float red[4];
    const int wid = tid >> 6, lane = tid & 63;
    if (lane == 0) red[wid] = m;
    __syncthreads();
    m = fmaxf(fmaxf(red[0], red[1]), fmaxf(red[2], red[3]));
    __syncthreads();

    v0.x = expf(v0.x - m); v0.y = expf(v0.y - m);
    v0.z = expf(v0.z - m); v0.w = expf(v0.w - m);
    v1.x = expf(v1.x - m); v1.y = expf(v1.y - m);
    v1.z = expf(v1.z - m); v1.w = expf(v1.w - m);

    float s = v0.x + v0.y + v0.z + v0.w + v1.x + v1.y + v1.z + v1.w;
#pragma unroll
    for (int off = 1; off < 64; off <<= 1) s += __shfl_xor(s, off);
    if (lane == 0) red[wid] = s;
    __syncthreads();
    s = red[0] + red[1] + red[2] + red[3];

    const float inv = 1.0f / s;
    v0.x *= inv; v0.y *= inv; v0.z *= inv; v0.w *= inv;
    v1.x *= inv; v1.y *= inv; v1.z *= inv; v1.w *= inv;

    ((float4*)p)[tid] = v0;
    ((float4*)p)[tid + 256] = v1;

    ushort4 o0, o1;
    o0.x = f2bf(v0.x); o0.y = f2bf(v0.y); o0.z = f2bf(v0.z); o0.w = f2bf(v0.w);
    o1.x = f2bf(v1.x); o1.y = f2bf(v1.y); o1.z = f2bf(v1.z); o1.w = f2bf(v1.w);
    ((ushort4*)pb)[tid] = o0;
    ((ushort4*)pb)[tid + 256] = o1;
}

extern "C" void kernel_launch(void* const* d_in, const int* in_sizes, int n_in,
                              void* d_out, int out_size, void* d_ws, size_t ws_size,
                              hipStream_t stream)
{
    const float* query = (const float*)d_in[0];   // (T,B,D)
    const float* x     = (const float*)d_in[1];   // (T,B,D)
    const float* w_in  = (const float*)d_in[2];   // (2D,D)
    const float* b_in  = (const float*)d_in[3];   // (2D,)
    const float* w_out = (const float*)d_in[4];   // (D,D)
    const float* b_out = (const float*)d_in[5];   // (D,)

    float* out_attn = (float*)d_out;                      // (T,B,D) fp32
    float* out_w    = out_attn + (long long)T * B * D;    // (B,T,T) fp32

    // workspace layout:
    //  [0,16)   xbf (cast->GEMM1)         then amid (PV->out_proj)
    //  [16,32)  qbf (cast->QK)
    //  [32,36)  wibf   [36,38) wobf
    //  [38,70)  kv (GEMM1->QK/transpose)  then Pbf (softmax->PV)
    //  [70,86)  vt (transpose->PV)
    char* ws = (char*)d_ws;
    ushort* xbf  = (ushort*)(ws);
    ushort* amid = (ushort*)(ws);
    ushort* qbf  = (ushort*)(ws + (16ll << 20));
    ushort* wibf = (ushort*)(ws + (32ll << 20));
    ushort* wobf = (ushort*)(ws + (36ll << 20));
    ushort* kv   = (ushort*)(ws + (38ll << 20));
    ushort* Pbf  = (ushort*)(ws + (38ll << 20));
    ushort* vt   = (ushort*)(ws + (70ll << 20));

    // allow 128 KiB dynamic LDS (one-time; host-side attr set, capture-safe)
    static bool attr_done = false;
    if (!attr_done) {
        (void)hipFuncSetAttribute(reinterpret_cast<const void*>(&gemm256<ushort>),
                                  hipFuncAttributeMaxDynamicSharedMemorySize, 131072);
        (void)hipFuncSetAttribute(reinterpret_cast<const void*>(&gemm256<float>),
                                  hipFuncAttributeMaxDynamicSharedMemorySize, 131072);
        attr_done = true;
    }

    // one cast launch for x, w_in, q, w_out
    cast_all<<<dim3(8192 + 2048 + 8192 + 1024), 256, 0, stream>>>(
        x, xbf, 8192, w_in, wibf, 2048, query, qbf, 8192, w_out, wobf, 1024);

    // 1) kv = X . Win^T + b_in       M=8192 N=2048 K=1024   (256 blocks, 256^2)
    gemm256<ushort><<<dim3(E / 256, M1 / 256, 1), 512, 131072, stream>>>(
        xbf, wibf, kv, b_in, D, D, D, E, 0, 0, 0, 1.0f);

    // 2) vt = transpose of V half
    transpose_v<<<dim3(T / 64, D / 64, B), 256, 0, stream>>>(kv, vt);

    // 3) logits[b,t,s] = (1/32) q . k   M=2048 N=2048 K=1024, batch B  (256 blocks, 256^2)
    gemm256<float><<<dim3(T / 256, T / 256, B), 512, 131072, stream>>>(
        qbf, kv, out_w, nullptr, D, B * D, B * E, T,
        (long long)D, (long long)E, (long long)T * T, 0.03125f);

    // 4) softmax rows in-place (output 1) + bf16 copy into Pbf
    softmax_kernel<<<dim3(B * T), 256, 0, stream>>>(out_w, Pbf);

    // 5) amid[t,b,d] = P . vt^T      M=2048 N=1024 K=2048, batch B   (512 blocks, 128^2)
    mfma_gemm_nt<ushort><<<dim3(D / 128, T / 128, B), 256, 0, stream>>>(
        Pbf, vt, amid, nullptr, T, T, T, B * D,
        (long long)T * T, (long long)D * T, (long long)D, 1.0f);

    // 6) out = amid . Wout^T + b_out  M=8192 N=1024 K=1024   (512 blocks, 128^2)
    mfma_gemm_nt<float><<<dim3(D / 128, M1 / 128, 1), 256, 0, stream>>>(
        amid, wobf, out_attn, b_out, D, D, D, D, 0, 0, 0, 1.0f);
}

// Round 11
// 348.832 us; speedup vs baseline: 1.9580x; 1.0091x over previous
//
#include <hip/hip_runtime.h>
#include <hip/hip_bf16.h>
#include <type_traits>

static constexpr int T = 2048;
static constexpr int B = 4;
static constexpr int D = 1024;
static constexpr int E = 2 * D;     // 2048
static constexpr int M1 = T * B;    // 8192

typedef __attribute__((ext_vector_type(8))) short short8;   // 8 bf16 = 4 VGPRs (MFMA A/B frag)
typedef __attribute__((ext_vector_type(4))) float f32x4;    // MFMA C/D frag

__device__ inline ushort f2bf(float x) {
    __hip_bfloat16 h = __float2bfloat16(x);
    return __builtin_bit_cast(ushort, h);
}

__device__ inline void glds16(const void* g, void* l) {
    __builtin_amdgcn_global_load_lds(
        (const __attribute__((address_space(1))) void*)g,
        (__attribute__((address_space(3))) void*)l, 16, 0, 0);
}

// XCD-aware bijective block swizzle (T1). ALL grids below have
// gridDim.x == 8 and per-z-slice block count divisible by 8, so XCD x
// (which receives original ids ≡ x mod 8) gets a contiguous bm-stripe:
// A-panels are fetched by exactly one XCD instead of all 8.
__device__ inline void xcd_swizzle(int& bn_i, int& bm_i) {
    int id = blockIdx.y * 8 + blockIdx.x;
    id = (id & 7) * gridDim.y + (id >> 3);   // bijective: nwg % 8 == 0
    bn_i = id & 7;
    bm_i = id >> 3;
}

// ===========================================================================
// 128x128-tile, BK=64, 4-wave 2-phase GEMM (NT): proven baseline structure.
//   C[m,n] = alpha * sum_k A[m,k]*Bt[n,k] + bias[n]
// LDS rows are 64 bf16 = 128B. XOR chunk swizzle: global 16B-chunk c of
// tile-row m lives at LDS chunk c ^ (m&7)  -> 2-way bank aliasing = free.
// ===========================================================================
template <typename OT>
__global__ __launch_bounds__(256) void mfma_gemm_nt(
    const ushort* __restrict__ A, const ushort* __restrict__ Bt,
    OT* __restrict__ C, const float* __restrict__ bias,
    int K, int lda, int ldb, int ldc,
    long long aBatch, long long bBatch, long long cBatch, float alpha)
{
    __shared__ ushort As[128 * 64];   // 16KB
    __shared__ ushort Bs[128 * 64];   // 16KB

    const int tid  = threadIdx.x;
    const int lane = tid & 63;
    const int wave = tid >> 6;        // 0..3
    const int wm = (wave & 1) * 64;
    const int wn = (wave >> 1) * 64;

    int bn_i, bm_i;
    xcd_swizzle(bn_i, bm_i);
    const int bm = bm_i * 128;
    const int bn = bn_i * 128;
    A  += blockIdx.z * aBatch;
    Bt += blockIdx.z * bBatch;
    C  += blockIdx.z * cBatch;

    f32x4 acc[4][4] = {};

    const int srow  = lane >> 3;                         // 0..7 within 8-row gang
    const int sElem = (((lane & 7) ^ (lane >> 3))) * 8;  // swizzled global elem offset
    const int rbase = ((lane >> 4) ^ (lane & 7)) * 8;    // kb=0 read chunk
    const int rxor4 = 4 * 8;                             // kb=1 flips bit2 of chunk

    for (int k0 = 0; k0 < K; k0 += 64) {
        __syncthreads();
#pragma unroll
        for (int j = 0; j < 4; ++j) {
            const int r = wave * 32 + j * 8;             // gang base row
            glds16(Bt + (long long)(bn + r + srow) * ldb + (k0 + sElem),
                   (void*)&Bs[r * 64]);
            glds16(A + (long long)(bm + r + srow) * lda + (k0 + sElem),
                   (void*)&As[r * 64]);
        }
        __syncthreads();

#pragma unroll
        for (int kb = 0; kb < 2; ++kb) {
            const int rElem = rbase ^ (kb ? rxor4 : 0);
            short8 af[4], bf[4];
#pragma unroll
            for (int i = 0; i < 4; ++i) {
                const int m = wm + i * 16 + (lane & 15);
                af[i] = *(const short8*)&As[m * 64 + rElem];
            }
#pragma unroll
            for (int j = 0; j < 4; ++j) {
                const int n = wn + j * 16 + (lane & 15);
                bf[j] = *(const short8*)&Bs[n * 64 + rElem];
            }
#pragma unroll
            for (int i = 0; i < 4; ++i)
#pragma unroll
                for (int j = 0; j < 4; ++j)
                    acc[i][j] = __builtin_amdgcn_mfma_f32_16x16x32_bf16(af[i], bf[j], acc[i][j], 0, 0, 0);
        }
    }

    // epilogue: C/D layout col=lane&15, row=(lane>>4)*4+r  [verified m89]
#pragma unroll
    for (int j = 0; j < 4; ++j) {
        const int col = bn + wn + j * 16 + (lane & 15);
        const float bv = bias ? bias[col] : 0.0f;
#pragma unroll
        for (int i = 0; i < 4; ++i) {
            const int row0 = bm + wm + i * 16 + ((lane >> 4) << 2);
#pragma unroll
            for (int r = 0; r < 4; ++r) {
                const float v = acc[i][j][r] * alpha + bv;
                if constexpr (std::is_same<OT, float>::value)
                    C[(long long)(row0 + r) * ldc + col] = v;
                else
                    C[(long long)(row0 + r) * ldc + col] = f2bf(v);
            }
        }
    }
}

// ===========================================================================
// 256x256-tile, BK=64, 8-wave (2M x 4N), 8-phase counted-vmcnt GEMM (NT).
// Schedule per K-tile t (parity P=t&1), 4 phases x 2 barriers; B-halves of
// t+1 staged in ph1/ph2 (opposite parity, always safe); A-halves of t+2
// staged in ph4 (same parity; safe: all A-reads of tile t completed by ph3's
// dep-wait + trailing barrier). vmcnt(4) once per tile (never 0 mid-loop).
// ===========================================================================

#define STAGE_A(p_, half_, t_) do {                                           \
    const int k0_ = (t_) << 6;                                                \
    _Pragma("unroll")                                                         \
    for (int i_ = 0; i_ < 2; ++i_) {                                          \
        const int r_ = (half_) * 128 + i_ * 64 + wave * 8;                    \
        glds16(A + ((bm + r_ + srow) * lda + k0_ + sElem),                    \
               (void*)&As[(p_) * 16384 + r_ * 64]);                           \
    } } while (0)

#define STAGE_B(p_, half_, t_) do {                                           \
    const int k0_ = (t_) << 6;                                                \
    _Pragma("unroll")                                                         \
    for (int i_ = 0; i_ < 2; ++i_) {                                          \
        const int r_ = (half_) * 128 + i_ * 64 + wave * 8;                    \
        glds16(Bt + ((bn + r_ + srow) * ldb + k0_ + sElem),                   \
               (void*)&Bs[(p_) * 16384 + r_ * 64]);                           \
    } } while (0)

#define READ_A(MOFF)                                                          \
    _Pragma("unroll") for (int i = 0; i < 4; ++i) {                           \
        const int m_ = wm + (MOFF) + i * 16 + l15;                            \
        af_[i][0] = *(const short8*)&as_[m_ * 64 + rbase];                    \
        af_[i][1] = *(const short8*)&as_[m_ * 64 + (rbase ^ 32)];             \
    }

#define READ_B(JOFF)                                                          \
    _Pragma("unroll") for (int j = 0; j < 2; ++j) {                           \
        const int n_ = wn + ((JOFF) + j) * 16 + l15;                          \
        bf_[(JOFF) + j][0] = *(const short8*)&bs_[n_ * 64 + rbase];           \
        bf_[(JOFF) + j][1] = *(const short8*)&bs_[n_ * 64 + (rbase ^ 32)];    \
    }

#define MFMA_QUAD(IOFF, JOFF)                                                 \
    _Pragma("unroll") for (int i = 0; i < 4; ++i)                             \
    _Pragma("unroll") for (int j = 0; j < 2; ++j)                             \
    _Pragma("unroll") for (int kb = 0; kb < 2; ++kb)                          \
        acc[(IOFF) + i][(JOFF) + j] = __builtin_amdgcn_mfma_f32_16x16x32_bf16(\
            af_[i][kb], bf_[(JOFF) + j][kb], acc[(IOFF) + i][(JOFF) + j], 0, 0, 0)

#define TILE(P_, TT_) {                                                       \
    const ushort* as_ = As + (P_) * 16384;                                    \
    const ushort* bs_ = Bs + (P_) * 16384;                                    \
    short8 af_[4][2], bf_[4][2];                                              \
    /* phase 1 */                                                             \
    READ_A(0)                                                                 \
    READ_B(0)                                                                 \
    if ((TT_) + 1 < NT) { STAGE_B((P_) ^ 1, 0, (TT_) + 1); }                  \
    __builtin_amdgcn_s_barrier();                                             \
    __builtin_amdgcn_s_setprio(1);                                            \
    MFMA_QUAD(0, 0);                                                          \
    __builtin_amdgcn_s_setprio(0);                                            \
    __builtin_amdgcn_s_barrier();                                             \
    /* phase 2 */                                                             \
    READ_B(2)                                                                 \
    if ((TT_) + 1 < NT) { STAGE_B((P_) ^ 1, 1, (TT_) + 1); }                  \
    __builtin_amdgcn_s_barrier();                                             \
    __builtin_amdgcn_s_setprio(1);                                            \
    MFMA_QUAD(0, 2);                                                          \
    __builtin_amdgcn_s_setprio(0);                                            \
    __builtin_amdgcn_s_barrier();                                             \
    /* phase 3 */                                                             \
    READ_A(64)                                                                \
    __builtin_amdgcn_s_barrier();                                             \
    __builtin_amdgcn_s_setprio(1);                                            \
    MFMA_QUAD(4, 0);                                                          \
    __builtin_amdgcn_s_setprio(0);                                            \
    __builtin_amdgcn_s_barrier();                                             \
    /* phase 4 */                                                             \
    if ((TT_) + 2 < NT) { STAGE_A((P_), 0, (TT_) + 2); STAGE_A((P_), 1, (TT_) + 2); } \
    __builtin_amdgcn_s_barrier();                                             \
    __builtin_amdgcn_s_setprio(1);                                            \
    MFMA_QUAD(4, 2);                                                          \
    __builtin_amdgcn_s_setprio(0);                                            \
    if ((TT_) + 2 < NT)      { asm volatile("s_waitcnt vmcnt(4)" ::: "memory"); } \
    else if ((TT_) + 1 < NT) { asm volatile("s_waitcnt vmcnt(0)" ::: "memory"); } \
    __builtin_amdgcn_s_barrier();                                             \
}

template <typename OT>
__global__ __launch_bounds__(512, 2) void gemm256(
    const ushort* __restrict__ A, const ushort* __restrict__ Bt,
    OT* __restrict__ C, const float* __restrict__ bias,
    int K, int lda, int ldb, int ldc,
    long long aBatch, long long bBatch, long long cBatch, float alpha)
{
    extern __shared__ ushort lds[];
    ushort* As = lds;                 // [2][256*64]
    ushort* Bs = lds + 2 * 16384;     // [2][256*64]

    const int tid  = threadIdx.x;
    const int lane = tid & 63;
    const int wave = tid >> 6;            // 0..7
    const int wm = (wave >> 2) * 128;     // 0 / 128
    const int wn = (wave & 3) * 64;       // 0 / 64 / 128 / 192
    const int l15 = lane & 15;

    int bn_i, bm_i;
    xcd_swizzle(bn_i, bm_i);
    const int bm = bm_i * 256;
    const int bn = bn_i * 256;
    A  += blockIdx.z * aBatch;
    Bt += blockIdx.z * bBatch;
    C  += blockIdx.z * cBatch;

    f32x4 acc[8][4] = {};

    const int srow  = lane >> 3;                         // row within 8-row gang
    const int sElem = ((lane & 7) ^ (lane >> 3)) * 8;    // swizzled global elem offset
    const int rbase = ((lane >> 4) ^ (lane & 7)) * 8;    // kb=0 read chunk (elems)

    const int NT = K >> 6;

    // prologue: tile0 fully + tile1's A halves in flight
    STAGE_A(0, 0, 0); STAGE_A(0, 1, 0);
    STAGE_B(0, 0, 0); STAGE_B(0, 1, 0);
    if (NT > 1) {
        STAGE_A(1, 0, 1); STAGE_A(1, 1, 1);
        asm volatile("s_waitcnt vmcnt(4)" ::: "memory");
    } else {
        asm volatile("s_waitcnt vmcnt(0)" ::: "memory");
    }
    __builtin_amdgcn_s_barrier();

    for (int t = 0; t < NT; t += 2) {   // NT even (K=1024/2048)
        TILE(0, t)
        TILE(1, t + 1)
    }

    // epilogue: C/D layout col=lane&15, row=(lane>>4)*4+r  [verified m89]
#pragma unroll
    for (int j = 0; j < 4; ++j) {
        const int col = bn + wn + j * 16 + l15;
        const float bv = bias ? bias[col] : 0.0f;
#pragma unroll
        for (int i = 0; i < 8; ++i) {
            const int row0 = bm + wm + i * 16 + ((lane >> 4) << 2);
#pragma unroll
            for (int r = 0; r < 4; ++r) {
                const float v = acc[i][j][r] * alpha + bv;
                if constexpr (std::is_same<OT, float>::value)
                    C[(long long)(row0 + r) * ldc + col] = v;
                else
                    C[(long long)(row0 + r) * ldc + col] = f2bf(v);
            }
        }
    }
}

#undef TILE
#undef MFMA_QUAD
#undef READ_A
#undef READ_B
#undef STAGE_A
#undef STAGE_B

// all four fp32->bf16 casts in one launch (region select by block index)
__global__ __launch_bounds__(256) void cast_all(
    const float* __restrict__ s0, ushort* __restrict__ d0, int n0,
    const float* __restrict__ s1, ushort* __restrict__ d1, int n1,
    const float* __restrict__ s2, ushort* __restrict__ d2, int n2,
    const float* __restrict__ s3, ushort* __restrict__ d3, int n3)
{
    int blk = blockIdx.x;
    const float* s; ushort* d;
    if (blk < n0) { s = s0; d = d0; }
    else if ((blk -= n0) < n1) { s = s1; d = d1; }
    else if ((blk -= n1) < n2) { s = s2; d = d2; }
    else { blk -= n2; s = s3; d = d3; }
    const int i = blk * 256 + threadIdx.x;
    const float4 v = ((const float4*)s)[i];
    ushort4 o;
    o.x = f2bf(v.x); o.y = f2bf(v.y); o.z = f2bf(v.z); o.w = f2bf(v.w);
    ((ushort4*)d)[i] = o;
}

// vt[b][d][s] = kv[(s*B+b)*E + D + d]   (64x64 LDS tile transpose per block)
__global__ __launch_bounds__(256) void transpose_v(const ushort* __restrict__ kv,
                                                   ushort* __restrict__ vt)
{
    __shared__ ushort tile[64][65];
    const int s0 = blockIdx.x * 64, d0 = blockIdx.y * 64, b = blockIdx.z;
    const int t = threadIdx.x;
    const int dl = (t & 15) * 4, sl = t >> 4;
#pragma unroll
    for (int p = 0; p < 4; ++p) {
        const int s = sl + p * 16;
        const ushort4 v = *(const ushort4*)&kv[((long long)(s0 + s) * B + b) * E + D + d0 + dl];
        tile[s][dl + 0] = v.x; tile[s][dl + 1] = v.y;
        tile[s][dl + 2] = v.z; tile[s][dl + 3] = v.w;
    }
    __syncthreads();
    const int dl2 = t >> 4, sl2 = (t & 15) * 4;
#pragma unroll
    for (int p = 0; p < 4; ++p) {
        const int d = dl2 + p * 16;
        ushort4 o;
        o.x = tile[sl2 + 0][d]; o.y = tile[sl2 + 1][d];
        o.z = tile[sl2 + 2][d]; o.w = tile[sl2 + 3][d];
        *(ushort4*)&vt[(long long)b * D * T + (long long)(d0 + d) * T + s0 + sl2] = o;
    }
}

// in-place fp32 softmax over rows of length T=2048, one 256-thr block per row.
// Also emits a bf16 copy of the row into Pbf for the PV GEMM.
// __expf: v_exp_f32-based fast exp (rel err ~1e-7, far below bf16 noise) —
// avoids the precise libm expf polynomial chain (~25-30 VALU/call x 16/thread).
__global__ __launch_bounds__(256) void softmax_kernel(float* __restrict__ W,
                                                      ushort* __restrict__ Pbf)
{
    const long long row = blockIdx.x;
    float* p = W + row * (long long)T;
    ushort* pb = Pbf + row * (long long)T;
    const int tid = threadIdx.x;

    float4 v0 = ((const float4*)p)[tid];
    float4 v1 = ((const float4*)p)[tid + 256];

    float m = fmaxf(fmaxf(fmaxf(v0.x, v0.y), fmaxf(v0.z, v0.w)),
                    fmaxf(fmaxf(v1.x, v1.y), fmaxf(v1.z, v1.w)));
#pragma unroll
    for (int off = 1; off < 64; off <<= 1) m = fmaxf(m, __shfl_xor(m, off));

    __shared__ float red[4];
    const int wid = tid >> 6, lane = tid & 63;
    if (lane == 0) red[wid] = m;
    __syncthreads();
    m = fmaxf(fmaxf(red[0], red[1]), fmaxf(red[2], red[3]));
    __syncthreads();

    v0.x = __expf(v0.x - m); v0.y = __expf(v0.y - m);
    v0.z = __expf(v0.z - m); v0.w = __expf(v0.w - m);
    v1.x = __expf(v1.x - m); v1.y = __expf(v1.y - m);
    v1.z = __expf(v1.z - m); v1.w = __expf(v1.w - m);

    float s = v0.x + v0.y + v0.z + v0.w + v1.x + v1.y + v1.z + v1.w;
#pragma unroll
    for (int off = 1; off < 64; off <<= 1) s += __shfl_xor(s, off);
    if (lane == 0) red[wid] = s;
    __syncthreads();
    s = red[0] + red[1] + red[2] + red[3];

    const float inv = 1.0f / s;
    v0.x *= inv; v0.y *= inv; v0.z *= inv; v0.w *= inv;
    v1.x *= inv; v1.y *= inv; v1.z *= inv; v1.w *= inv;

    ((float4*)p)[tid] = v0;
    ((float4*)p)[tid + 256] = v1;

    ushort4 o0, o1;
    o0.x = f2bf(v0.x); o0.y = f2bf(v0.y); o0.z = f2bf(v0.z); o0.w = f2bf(v0.w);
    o1.x = f2bf(v1.x); o1.y = f2bf(v1.y); o1.z = f2bf(v1.z); o1.w = f2bf(v1.w);
    ((ushort4*)pb)[tid] = o0;
    ((ushort4*)pb)[tid + 256] = o1;
}

extern "C" void kernel_launch(void* const* d_in, const int* in_sizes, int n_in,
                              void* d_out, int out_size, void* d_ws, size_t ws_size,
                              hipStream_t stream)
{
    const float* query = (const float*)d_in[0];   // (T,B,D)
    const float* x     = (const float*)d_in[1];   // (T,B,D)
    const float* w_in  = (const float*)d_in[2];   // (2D,D)
    const float* b_in  = (const float*)d_in[3];   // (2D,)
    const float* w_out = (const float*)d_in[4];   // (D,D)
    const float* b_out = (const float*)d_in[5];   // (D,)

    float* out_attn = (float*)d_out;                      // (T,B,D) fp32
    float* out_w    = out_attn + (long long)T * B * D;    // (B,T,T) fp32

    // workspace layout:
    //  [0,16)   xbf (cast->GEMM1)         then amid (PV->out_proj)
    //  [16,32)  qbf (cast->QK)
    //  [32,36)  wibf   [36,38) wobf
    //  [38,70)  kv (GEMM1->QK/transpose)  then Pbf (softmax->PV)
    //  [70,86)  vt (transpose->PV)
    char* ws = (char*)d_ws;
    ushort* xbf  = (ushort*)(ws);
    ushort* amid = (ushort*)(ws);
    ushort* qbf  = (ushort*)(ws + (16ll << 20));
    ushort* wibf = (ushort*)(ws + (32ll << 20));
    ushort* wobf = (ushort*)(ws + (36ll << 20));
    ushort* kv   = (ushort*)(ws + (38ll << 20));
    ushort* Pbf  = (ushort*)(ws + (38ll << 20));
    ushort* vt   = (ushort*)(ws + (70ll << 20));

    // allow 128 KiB dynamic LDS (one-time; host-side attr set, capture-safe)
    static bool attr_done = false;
    if (!attr_done) {
        (void)hipFuncSetAttribute(reinterpret_cast<const void*>(&gemm256<ushort>),
                                  hipFuncAttributeMaxDynamicSharedMemorySize, 131072);
        (void)hipFuncSetAttribute(reinterpret_cast<const void*>(&gemm256<float>),
                                  hipFuncAttributeMaxDynamicSharedMemorySize, 131072);
        attr_done = true;
    }

    // one cast launch for x, w_in, q, w_out
    cast_all<<<dim3(8192 + 2048 + 8192 + 1024), 256, 0, stream>>>(
        x, xbf, 8192, w_in, wibf, 2048, query, qbf, 8192, w_out, wobf, 1024);

    // 1) kv = X . Win^T + b_in       M=8192 N=2048 K=1024   (256 blocks, 256^2)
    gemm256<ushort><<<dim3(E / 256, M1 / 256, 1), 512, 131072, stream>>>(
        xbf, wibf, kv, b_in, D, D, D, E, 0, 0, 0, 1.0f);

    // 2) vt = transpose of V half
    transpose_v<<<dim3(T / 64, D / 64, B), 256, 0, stream>>>(kv, vt);

    // 3) logits[b,t,s] = (1/32) q . k   M=2048 N=2048 K=1024, batch B  (256 blocks, 256^2)
    gemm256<float><<<dim3(T / 256, T / 256, B), 512, 131072, stream>>>(
        qbf, kv, out_w, nullptr, D, B * D, B * E, T,
        (long long)D, (long long)E, (long long)T * T, 0.03125f);

    // 4) softmax rows in-place (output 1) + bf16 copy into Pbf
    softmax_kernel<<<dim3(B * T), 256, 0, stream>>>(out_w, Pbf);

    // 5) amid[t,b,d] = P . vt^T      M=2048 N=1024 K=2048, batch B   (512 blocks, 128^2)
    mfma_gemm_nt<ushort><<<dim3(D / 128, T / 128, B), 256, 0, stream>>>(
        Pbf, vt, amid, nullptr, T, T, T, B * D,
        (long long)T * T, (long long)D * T, (long long)D, 1.0f);

    // 6) out = amid . Wout^T + b_out  M=8192 N=1024 K=1024   (512 blocks, 128^2)
    mfma_gemm_nt<float><<<dim3(D / 128, M1 / 128, 1), 256, 0, stream>>>(
        amid, wobf, out_attn, b_out, D, D, D, D, 0, 0, 0, 1.0f);
}